// Round 1
// baseline (2432.687 us; speedup 1.0000x reference)
//
#include <hip/hip_runtime.h>

#define NB 4
#define CIN 512
#define NPIX 4096
#define CQK 64
#define COUT 256

// ---------- transpose per batch: src [rows][cols] -> dst [cols][rows] ----------
__global__ __launch_bounds__(256) void transpose_k(const float* __restrict__ src,
                                                   float* __restrict__ dst,
                                                   int rows, int cols) {
  __shared__ float tile[32][33];
  const int b = blockIdx.z;
  const int c0 = blockIdx.x * 32;
  const int r0 = blockIdx.y * 32;
  const float* s = src + (size_t)b * rows * cols;
  float* d = dst + (size_t)b * rows * cols;
  const int tx = threadIdx.x, ty = threadIdx.y;  // 32 x 8
#pragma unroll
  for (int i = 0; i < 32; i += 8)
    tile[ty + i][tx] = s[(size_t)(r0 + ty + i) * cols + (c0 + tx)];
  __syncthreads();
#pragma unroll
  for (int i = 0; i < 32; i += 8)
    d[(size_t)(c0 + ty + i) * rows + (r0 + tx)] = tile[tx][ty + i];
}

// ---------- out[r][o] = sum_c A[r][c] * W[o][c] + bias[o] ----------
// A: [R][512] row-major (xT), W: [O][512], 64x64 block tile, 4x4 micro-tile
__global__ __launch_bounds__(256) void gemm_qkv_k(const float* __restrict__ A,
                                                  const float* __restrict__ W,
                                                  const float* __restrict__ bias,
                                                  float* __restrict__ out, int O) {
  __shared__ float As[16][68];  // [k][row]
  __shared__ float Bs[16][68];  // [k][col]
  const int r0 = blockIdx.x * 64;
  const int o0 = blockIdx.y * 64;
  const int t = threadIdx.x;
  const int tx = t & 15, ty = t >> 4;
  const int li = t >> 2;         // 0..63
  const int lu = (t & 3) * 4;    // 0,4,8,12
  float acc[4][4] = {};
  for (int kc = 0; kc < CIN; kc += 16) {
    float4 av = *(const float4*)(A + (size_t)(r0 + li) * CIN + kc + lu);
    float4 bv = *(const float4*)(W + (size_t)(o0 + li) * CIN + kc + lu);
    __syncthreads();
    As[lu + 0][li] = av.x; As[lu + 1][li] = av.y; As[lu + 2][li] = av.z; As[lu + 3][li] = av.w;
    Bs[lu + 0][li] = bv.x; Bs[lu + 1][li] = bv.y; Bs[lu + 2][li] = bv.z; Bs[lu + 3][li] = bv.w;
    __syncthreads();
#pragma unroll
    for (int k = 0; k < 16; k++) {
      const float4 a4 = *(const float4*)&As[k][ty * 4];
      const float4 b4 = *(const float4*)&Bs[k][tx * 4];
      const float aa[4] = {a4.x, a4.y, a4.z, a4.w};
      const float bb[4] = {b4.x, b4.y, b4.z, b4.w};
#pragma unroll
      for (int u = 0; u < 4; u++)
#pragma unroll
        for (int v = 0; v < 4; v++) acc[u][v] += aa[u] * bb[v];
    }
  }
#pragma unroll
  for (int u = 0; u < 4; u++) {
    float4 res;
    res.x = acc[u][0] + bias[o0 + tx * 4 + 0];
    res.y = acc[u][1] + bias[o0 + tx * 4 + 1];
    res.z = acc[u][2] + bias[o0 + tx * 4 + 2];
    res.w = acc[u][3] + bias[o0 + tx * 4 + 3];
    *(float4*)(out + (size_t)(r0 + ty * 4 + u) * O + o0 + tx * 4) = res;
  }
}

// ---------- flash attention + residual ----------
// Qt,Kt: [B][N][64]; Vt,xT,paT: [B][N][512]
// block = 256 threads, 32 query rows; wave w owns S-rows w*8..w*8+7 and the
// same rows in the PV accumulator (all softmax state deps are intra-wave).
__global__ __launch_bounds__(256) void attn_k(const float* __restrict__ Qt,
                                              const float* __restrict__ Kt,
                                              const float* __restrict__ Vt,
                                              const float* __restrict__ xT,
                                              float* __restrict__ paT) {
  const int b = blockIdx.y;
  const int m0 = blockIdx.x * 32;
  const int t = threadIdx.x;
  __shared__ float Qs[32][68];    // [m][k]
  __shared__ float Kst[64][68];   // [k][j]
  __shared__ float Ps[32][68];    // [m][j]
  __shared__ float mrun[32], lrun[32], alpha_s[32];

  {
    const int i = t >> 3;
    const int k8 = (t & 7) * 8;
    const float* qp = Qt + ((size_t)b * NPIX + m0 + i) * CQK + k8;
    const float4 q0 = *(const float4*)qp;
    const float4 q1 = *(const float4*)(qp + 4);
    Qs[i][k8 + 0] = q0.x; Qs[i][k8 + 1] = q0.y; Qs[i][k8 + 2] = q0.z; Qs[i][k8 + 3] = q0.w;
    Qs[i][k8 + 4] = q1.x; Qs[i][k8 + 5] = q1.y; Qs[i][k8 + 6] = q1.z; Qs[i][k8 + 7] = q1.w;
  }
  if (t < 32) { mrun[t] = -1e30f; lrun[t] = 0.0f; }

  const int sm = t >> 3;        // S row 0..31
  const int jg = t & 7;         // S col group
  const int rg = t >> 6;        // PV row group (== wave id)
  const int c0 = (t & 63) * 8;  // PV channel base
  float acc[8][8] = {};

  for (int n0 = 0; n0 < NPIX; n0 += 64) {
    {  // stage K tile transposed: Kst[k][j]
      const int j = t >> 2;
      const int k16 = (t & 3) * 16;
      const float* kp = Kt + ((size_t)b * NPIX + n0 + j) * CQK + k16;
#pragma unroll
      for (int u = 0; u < 16; u += 4) {
        const float4 kv = *(const float4*)(kp + u);
        Kst[k16 + u + 0][j] = kv.x;
        Kst[k16 + u + 1][j] = kv.y;
        Kst[k16 + u + 2][j] = kv.z;
        Kst[k16 + u + 3][j] = kv.w;
      }
    }
    __syncthreads();
    // S[sm][jg*8 .. +7]
    float s[8] = {};
#pragma unroll 8
    for (int k = 0; k < 64; k++) {
      const float qv = Qs[sm][k];
      const float4 k0 = *(const float4*)&Kst[k][jg * 8];
      const float4 k1 = *(const float4*)&Kst[k][jg * 8 + 4];
      s[0] += qv * k0.x; s[1] += qv * k0.y; s[2] += qv * k0.z; s[3] += qv * k0.w;
      s[4] += qv * k1.x; s[5] += qv * k1.y; s[6] += qv * k1.z; s[7] += qv * k1.w;
    }
    // online softmax: reduce across the 8 lanes sharing row sm
    float tmax = s[0];
#pragma unroll
    for (int u = 1; u < 8; u++) tmax = fmaxf(tmax, s[u]);
    tmax = fmaxf(tmax, __shfl_xor(tmax, 1));
    tmax = fmaxf(tmax, __shfl_xor(tmax, 2));
    tmax = fmaxf(tmax, __shfl_xor(tmax, 4));
    const float mprev = mrun[sm];
    const float mnew = fmaxf(mprev, tmax);
    const float al = __expf(mprev - mnew);
    float psum = 0.0f;
#pragma unroll
    for (int u = 0; u < 8; u++) { s[u] = __expf(s[u] - mnew); psum += s[u]; }
    psum += __shfl_xor(psum, 1);
    psum += __shfl_xor(psum, 2);
    psum += __shfl_xor(psum, 4);
    if (jg == 0) {
      mrun[sm] = mnew;
      lrun[sm] = lrun[sm] * al + psum;
      alpha_s[sm] = al;
    }
    *(float4*)&Ps[sm][jg * 8] = make_float4(s[0], s[1], s[2], s[3]);
    *(float4*)&Ps[sm][jg * 8 + 4] = make_float4(s[4], s[5], s[6], s[7]);
    __syncthreads();
    // PV: acc[r][c] = acc*alpha + sum_j P[r][j] * V[n0+j][c]
#pragma unroll
    for (int r = 0; r < 8; r++) {
      const float a = alpha_s[rg * 8 + r];
#pragma unroll
      for (int c = 0; c < 8; c++) acc[r][c] *= a;
    }
    const float* vbase = Vt + ((size_t)b * NPIX + n0) * CIN + c0;
#pragma unroll 4
    for (int j = 0; j < 64; j++) {
      const float4 v0 = *(const float4*)(vbase + (size_t)j * CIN);
      const float4 v1 = *(const float4*)(vbase + (size_t)j * CIN + 4);
      const float vv[8] = {v0.x, v0.y, v0.z, v0.w, v1.x, v1.y, v1.z, v1.w};
#pragma unroll
      for (int r = 0; r < 8; r++) {
        const float p = Ps[rg * 8 + r][j];
#pragma unroll
        for (int c = 0; c < 8; c++) acc[r][c] += p * vv[c];
      }
    }
    __syncthreads();
  }
  // epilogue: normalize + residual, write paT
#pragma unroll
  for (int r = 0; r < 8; r++) {
    const int m = m0 + rg * 8 + r;
    const float linv = 1.0f / lrun[rg * 8 + r];
    const float* xp = xT + ((size_t)b * NPIX + m) * CIN + c0;
    float* pp = paT + ((size_t)b * NPIX + m) * CIN + c0;
    const float4 x0 = *(const float4*)xp;
    const float4 x1 = *(const float4*)(xp + 4);
    float4 r0, r1;
    r0.x = acc[r][0] * linv + x0.x;
    r0.y = acc[r][1] * linv + x0.y;
    r0.z = acc[r][2] * linv + x0.z;
    r0.w = acc[r][3] * linv + x0.w;
    r1.x = acc[r][4] * linv + x1.x;
    r1.y = acc[r][5] * linv + x1.y;
    r1.z = acc[r][6] * linv + x1.z;
    r1.w = acc[r][7] * linv + x1.w;
    *(float4*)pp = r0;
    *(float4*)(pp + 4) = r1;
  }
}

// ---------- spatial pooling partials over 64-row chunks ----------
__global__ __launch_bounds__(256) void pool_k(const float* __restrict__ paT,
                                              float* __restrict__ psum,
                                              float* __restrict__ pmax) {
  const int b = blockIdx.x >> 6;
  const int ch = blockIdx.x & 63;
  const int t = threadIdx.x;
#pragma unroll
  for (int h = 0; h < 2; h++) {
    const int c = t + h * 256;
    const float* base = paT + ((size_t)b * NPIX + ch * 64) * CIN + c;
    float sacc = 0.0f, macc = -1e30f;
    for (int n = 0; n < 64; n++) {
      const float v = base[(size_t)n * CIN];
      sacc += v;
      macc = fmaxf(macc, v);
    }
    psum[((size_t)b * 64 + ch) * CIN + c] = sacc;
    pmax[((size_t)b * 64 + ch) * CIN + c] = macc;
  }
}

// ---------- channel-attention MLP -> sigmoid scale ----------
__global__ __launch_bounds__(256) void mlp_k(const float* __restrict__ psum,
                                             const float* __restrict__ pmax,
                                             const float* __restrict__ w1,
                                             const float* __restrict__ w2,
                                             float* __restrict__ scale) {
  const int b = blockIdx.x;
  const int t = threadIdx.x;
  __shared__ float avg_l[CIN], max_l[CIN], hbuf[128];
#pragma unroll
  for (int h = 0; h < 2; h++) {
    const int c = t + h * 256;
    float sacc = 0.0f, macc = -1e30f;
    for (int ch = 0; ch < 64; ch++) {
      sacc += psum[((size_t)b * 64 + ch) * CIN + c];
      macc = fmaxf(macc, pmax[((size_t)b * 64 + ch) * CIN + c]);
    }
    avg_l[c] = sacc * (1.0f / 4096.0f);
    max_l[c] = macc;
  }
  __syncthreads();
  if (t < 128) {
    const float* src = (t < 64) ? avg_l : max_l;
    const int o = t & 63;
    float sacc = 0.0f;
    for (int c = 0; c < CIN; c++) sacc += w1[o * CIN + c] * src[c];
    hbuf[t] = fmaxf(sacc, 0.0f);
  }
  __syncthreads();
#pragma unroll
  for (int h = 0; h < 2; h++) {
    const int c = t + h * 256;
    float sacc = 0.0f;
#pragma unroll
    for (int k = 0; k < 64; k++) sacc += w2[c * 64 + k] * (hbuf[k] + hbuf[64 + k]);
    scale[b * CIN + c] = 1.0f / (1.0f + __expf(-sacc));
  }
}

// ---------- 3x3 conv + BN(eval) + ReLU, scale fused at input staging ----------
// pa: [B][512][64][64]; out: [B][256][64][64]
// block: 32x16 pixel tile, 16 output channels, 2 pixels/thread
__global__ __launch_bounds__(256) void conv_k(const float* __restrict__ pa,
                                              const float* __restrict__ scale,
                                              const float* __restrict__ cw,
                                              const float* __restrict__ gamma,
                                              const float* __restrict__ beta,
                                              const float* __restrict__ mean,
                                              const float* __restrict__ var,
                                              float* __restrict__ out) {
  const int b = blockIdx.z;
  const int o0 = blockIdx.y * 16;
  const int bx = blockIdx.x;
  const int ty0 = (bx >> 2) * 32;
  const int tx0 = (bx & 3) * 16;
  const int t = threadIdx.x;
  __shared__ float in_s[8][612];   // [c][34*18] c-major => stride-1 across lanes
  __shared__ float w_s[1152];      // [(c*9+tap)*16 + o]
  __shared__ float sb[16], bb[16];
  if (t < 16) {
    const int o = o0 + t;
    const float inv = rsqrtf(var[o] + 1e-5f);
    const float sc = inv * gamma[o];
    sb[t] = sc;
    bb[t] = beta[o] - mean[o] * sc;
  }
  float acc[2][16] = {};
  const int lx = t & 15;
  const int ly = t >> 4;
  for (int cc = 0; cc < CIN; cc += 8) {
    __syncthreads();
#pragma unroll
    for (int c = 0; c < 8; c++) {
      const float sc = scale[b * CIN + cc + c];
      const float* src = pa + ((size_t)(b * CIN + cc + c)) * NPIX;
      for (int pix = t; pix < 612; pix += 256) {
        const int py = pix / 18;
        const int px = pix - py * 18;
        const int gy = ty0 - 1 + py;
        const int gx = tx0 - 1 + px;
        float v = 0.0f;
        if (gy >= 0 && gy < 64 && gx >= 0 && gx < 64) v = src[gy * 64 + gx] * sc;
        in_s[c][pix] = v;
      }
    }
    for (int idx = t; idx < 1152; idx += 256) {
      const int o = idx / 72;
      const int r = idx - o * 72;  // r = c*9 + tap
      w_s[r * 16 + o] = cw[(size_t)(o0 + o) * 4608 + cc * 9 + r];
    }
    __syncthreads();
#pragma unroll
    for (int c = 0; c < 8; c++) {
#pragma unroll
      for (int tap = 0; tap < 9; tap++) {
        const int ky = tap / 3, kx = tap - ky * 3;
        const float xv0 = in_s[c][(ly * 2 + ky) * 18 + lx + kx];
        const float xv1 = in_s[c][(ly * 2 + 1 + ky) * 18 + lx + kx];
        const float4* wp = (const float4*)&w_s[(c * 9 + tap) * 16];
        const float4 w0 = wp[0], w1 = wp[1], w2 = wp[2], w3 = wp[3];
        const float wv[16] = {w0.x, w0.y, w0.z, w0.w, w1.x, w1.y, w1.z, w1.w,
                              w2.x, w2.y, w2.z, w2.w, w3.x, w3.y, w3.z, w3.w};
#pragma unroll
        for (int o = 0; o < 16; o++) {
          acc[0][o] += xv0 * wv[o];
          acc[1][o] += xv1 * wv[o];
        }
      }
    }
  }
#pragma unroll
  for (int o = 0; o < 16; o++) {
    const float s = sb[o], bi = bb[o];
#pragma unroll
    for (int p = 0; p < 2; p++) {
      const int gy = ty0 + ly * 2 + p;
      const int gx = tx0 + lx;
      const float y = acc[p][o] * s + bi;
      out[((size_t)(b * COUT + o0 + o)) * NPIX + gy * 64 + gx] = fmaxf(y, 0.0f);
    }
  }
}

extern "C" void kernel_launch(void* const* d_in, const int* in_sizes, int n_in,
                              void* d_out, int out_size, void* d_ws, size_t ws_size,
                              hipStream_t stream) {
  (void)in_sizes; (void)n_in; (void)out_size; (void)ws_size;
  const float* x       = (const float*)d_in[0];
  const float* wq      = (const float*)d_in[1];
  const float* bq      = (const float*)d_in[2];
  const float* wk      = (const float*)d_in[3];
  const float* bk      = (const float*)d_in[4];
  const float* wv      = (const float*)d_in[5];
  const float* bv      = (const float*)d_in[6];
  const float* ca_w1   = (const float*)d_in[7];
  const float* ca_w2   = (const float*)d_in[8];
  const float* conv_w  = (const float*)d_in[9];
  const float* bn_gamma= (const float*)d_in[10];
  const float* bn_beta = (const float*)d_in[11];
  const float* bn_mean = (const float*)d_in[12];
  const float* bn_var  = (const float*)d_in[13];
  float* out = (float*)d_out;

  float* ws  = (float*)d_ws;
  float* xT  = ws;                    // [B][N][C]   8388608
  float* Qt  = xT + 8388608;          // [B][N][64]  1048576
  float* Kt  = Qt + 1048576;          // [B][N][64]  1048576
  float* Vt  = Kt + 1048576;          // [B][N][C]   8388608
  float* paT = Vt + 8388608;          // [B][N][C]   8388608
  float* pa  = xT;                    // alias: xT dead after attn_k
  float* psum = paT + 8388608;        // [B][64][C]  131072
  float* pmax = psum + 131072;        // [B][64][C]  131072
  float* scl  = pmax + 131072;        // [B][C]      2048

  const dim3 tb(32, 8, 1);
  // x [B][C][N] -> xT [B][N][C]
  transpose_k<<<dim3(NPIX / 32, CIN / 32, NB), tb, 0, stream>>>(x, xT, CIN, NPIX);
  // Q,K,V projections (rows = B*N, batch-independent)
  gemm_qkv_k<<<dim3(256, 1, 1), 256, 0, stream>>>(xT, wq, bq, Qt, 64);
  gemm_qkv_k<<<dim3(256, 1, 1), 256, 0, stream>>>(xT, wk, bk, Kt, 64);
  gemm_qkv_k<<<dim3(256, 8, 1), 256, 0, stream>>>(xT, wv, bv, Vt, 512);
  // flash attention + residual -> paT [B][N][C]
  attn_k<<<dim3(NPIX / 32, NB, 1), 256, 0, stream>>>(Qt, Kt, Vt, xT, paT);
  // paT -> pa [B][C][N] for conv
  transpose_k<<<dim3(CIN / 32, NPIX / 32, NB), tb, 0, stream>>>(paT, pa, NPIX, CIN);
  // channel attention
  pool_k<<<dim3(NB * 64, 1, 1), 256, 0, stream>>>(paT, psum, pmax);
  mlp_k<<<dim3(NB, 1, 1), 256, 0, stream>>>(psum, pmax, ca_w1, ca_w2, scl);
  // conv + BN + ReLU (scale fused at staging)
  conv_k<<<dim3(8, 16, NB), 256, 0, stream>>>(pa, scl, conv_w, bn_gamma, bn_beta,
                                              bn_mean, bn_var, out);
}

// Round 2
// 1552.521 us; speedup vs baseline: 1.5669x; 1.5669x over previous
//
#include <hip/hip_runtime.h>

#define NB 4
#define CIN 512
#define NPIX 4096
#define CQK 64
#define COUT 256

typedef __bf16 bh16;
typedef __attribute__((ext_vector_type(8))) __bf16 bf16x8;
typedef __attribute__((ext_vector_type(16))) float f32x16;

#define AS1 __attribute__((address_space(1)))
#define AS3 __attribute__((address_space(3)))

__device__ __forceinline__ void glds16(const void* g, void* l) {
  __builtin_amdgcn_global_load_lds((const AS1 unsigned int*)g, (AS3 unsigned int*)l, 16, 0, 0);
}

// ---------- transpose per batch: src [rows][cols] -> dst [cols][rows] ----------
__global__ __launch_bounds__(256) void transpose_k(const float* __restrict__ src,
                                                   float* __restrict__ dst,
                                                   int rows, int cols) {
  __shared__ float tile[32][33];
  const int b = blockIdx.z;
  const int c0 = blockIdx.x * 32;
  const int r0 = blockIdx.y * 32;
  const float* s = src + (size_t)b * rows * cols;
  float* d = dst + (size_t)b * rows * cols;
  const int tx = threadIdx.x, ty = threadIdx.y;  // 32 x 8
#pragma unroll
  for (int i = 0; i < 32; i += 8)
    tile[ty + i][tx] = s[(size_t)(r0 + ty + i) * cols + (c0 + tx)];
  __syncthreads();
#pragma unroll
  for (int i = 0; i < 32; i += 8)
    d[(size_t)(c0 + ty + i) * rows + (r0 + tx)] = tile[tx][ty + i];
}

// ---------- Q/K projection: out[r][o] = sum_c A[r][c]*W[o][c] + bias[o], bf16 out ----------
__global__ __launch_bounds__(256) void gemm_qkv_k(const float* __restrict__ A,
                                                  const float* __restrict__ W,
                                                  const float* __restrict__ bias,
                                                  bh16* __restrict__ out, int O) {
  __shared__ float As[16][68];  // [k][row]
  __shared__ float Bs[16][68];  // [k][col]
  const int r0 = blockIdx.x * 64;
  const int o0 = blockIdx.y * 64;
  const int t = threadIdx.x;
  const int tx = t & 15, ty = t >> 4;
  const int li = t >> 2;
  const int lu = (t & 3) * 4;
  float acc[4][4] = {};
  for (int kc = 0; kc < CIN; kc += 16) {
    float4 av = *(const float4*)(A + (size_t)(r0 + li) * CIN + kc + lu);
    float4 bv = *(const float4*)(W + (size_t)(o0 + li) * CIN + kc + lu);
    __syncthreads();
    As[lu + 0][li] = av.x; As[lu + 1][li] = av.y; As[lu + 2][li] = av.z; As[lu + 3][li] = av.w;
    Bs[lu + 0][li] = bv.x; Bs[lu + 1][li] = bv.y; Bs[lu + 2][li] = bv.z; Bs[lu + 3][li] = bv.w;
    __syncthreads();
#pragma unroll
    for (int k = 0; k < 16; k++) {
      const float4 a4 = *(const float4*)&As[k][ty * 4];
      const float4 b4 = *(const float4*)&Bs[k][tx * 4];
      const float aa[4] = {a4.x, a4.y, a4.z, a4.w};
      const float bb[4] = {b4.x, b4.y, b4.z, b4.w};
#pragma unroll
      for (int u = 0; u < 4; u++)
#pragma unroll
        for (int v = 0; v < 4; v++) acc[u][v] += aa[u] * bb[v];
    }
  }
#pragma unroll
  for (int u = 0; u < 4; u++) {
    union { bh16 h[4]; uint2 u2; } pk;
#pragma unroll
    for (int v = 0; v < 4; v++) pk.h[v] = (bh16)(acc[u][v] + bias[o0 + tx * 4 + v]);
    *(uint2*)(void*)(out + (size_t)(r0 + ty * 4 + u) * O + o0 + tx * 4) = pk.u2;
  }
}

// ---------- V projection: Vc[o][n] = sum_c wv[o][c]*x[c][n] + bv[o], bf16 [B][C][N] ----------
__global__ __launch_bounds__(256) void gemm_v_k(const float* __restrict__ x,
                                                const float* __restrict__ wv,
                                                const float* __restrict__ bv,
                                                bh16* __restrict__ Vc) {
  __shared__ float As[16][68];  // [k][o]
  __shared__ float Bs[16][68];  // [k][n]
  const int n0 = blockIdx.x * 64;
  const int o0 = blockIdx.y * 64;
  const int b = blockIdx.z;
  const int t = threadIdx.x;
  const int tx = t & 15, ty = t >> 4;
  const int li = t >> 2;
  const int lu = (t & 3) * 4;
  float acc[4][4] = {};
  for (int kc = 0; kc < CIN; kc += 16) {
    float4 av = *(const float4*)(wv + (size_t)(o0 + li) * CIN + kc + lu);
    float4 bx = *(const float4*)(x + ((size_t)b * CIN + kc + ty) * NPIX + n0 + tx * 4);
    __syncthreads();
    As[lu + 0][li] = av.x; As[lu + 1][li] = av.y; As[lu + 2][li] = av.z; As[lu + 3][li] = av.w;
    *(float4*)&Bs[ty][tx * 4] = bx;
    __syncthreads();
#pragma unroll
    for (int k = 0; k < 16; k++) {
      const float4 a4 = *(const float4*)&As[k][ty * 4];
      const float4 b4 = *(const float4*)&Bs[k][tx * 4];
      const float aa[4] = {a4.x, a4.y, a4.z, a4.w};
      const float bb[4] = {b4.x, b4.y, b4.z, b4.w};
#pragma unroll
      for (int u = 0; u < 4; u++)
#pragma unroll
        for (int v = 0; v < 4; v++) acc[u][v] += aa[u] * bb[v];
    }
  }
#pragma unroll
  for (int u = 0; u < 4; u++) {
    const int o = o0 + ty * 4 + u;
    union { bh16 h[4]; uint2 u2; } pk;
#pragma unroll
    for (int v = 0; v < 4; v++) pk.h[v] = (bh16)(acc[u][v] + bv[o]);
    *(uint2*)(void*)(Vc + ((size_t)(b * CIN + o)) * NPIX + n0 + tx * 4) = pk.u2;
  }
}

// ---------- pass 1: softmax stats (row max, 1/rowsum) via MFMA QK^T ----------
// S^T[j][m] tiles; lane owns column m -> stats are lane-local + shfl_xor(32).
__global__ __launch_bounds__(256) void attn_stats_k(const bh16* __restrict__ Qt,
                                                    const bh16* __restrict__ Kt,
                                                    float* __restrict__ mstat,
                                                    float* __restrict__ linv) {
  const int mblk = blockIdx.x * 64;
  const int b = blockIdx.y;
  const int t = threadIdx.x;
  const int w = t >> 6, lane = t & 63, l31 = lane & 31, hi = lane >> 5;
  const int w64 = w << 6;
  __shared__ __align__(16) bh16 Qs[8 * 64 * 8];
  __shared__ __align__(16) bh16 Ks[8 * 64 * 8];
  __shared__ float smax[4][32], ssum[4][32];

#pragma unroll
  for (int i = 0; i < 2; i++) {
    const int s = i * 256 + t;
    const int d8 = s >> 6, m = s & 63;
    glds16(Qt + ((size_t)(b * NPIX + mblk + m)) * CQK + d8 * 8, &Qs[(size_t)(i * 256 + w64) * 8]);
  }
  const int j0 = (w & 1) * 32;
  const int m0 = (w >> 1) * 32;
  float rmax = -1e30f, rsum = 0.0f;

  for (int n0 = 0; n0 < NPIX; n0 += 64) {
    __syncthreads();
#pragma unroll
    for (int i = 0; i < 2; i++) {
      const int s = i * 256 + t;
      const int d8 = s >> 6, j = s & 63;
      glds16(Kt + ((size_t)(b * NPIX + n0 + j)) * CQK + d8 * 8, &Ks[(size_t)(i * 256 + w64) * 8]);
    }
    __syncthreads();
    f32x16 s1;
#pragma unroll
    for (int r = 0; r < 16; r++) s1[r] = 0.0f;
#pragma unroll
    for (int ks = 0; ks < 4; ks++) {
      bf16x8 a = *(const bf16x8*)&Ks[(size_t)((ks * 2 + hi) * 64 + j0 + l31) * 8];
      bf16x8 bq = *(const bf16x8*)&Qs[(size_t)((ks * 2 + hi) * 64 + m0 + l31) * 8];
      s1 = __builtin_amdgcn_mfma_f32_32x32x16_bf16(a, bq, s1, 0, 0, 0);
    }
    float tmax = s1[0];
#pragma unroll
    for (int r = 1; r < 16; r++) tmax = fmaxf(tmax, s1[r]);
    tmax = fmaxf(tmax, __shfl_xor(tmax, 32));
    const float nm = fmaxf(rmax, tmax);
    float esum = 0.0f;
#pragma unroll
    for (int r = 0; r < 16; r++) esum += __expf(s1[r] - nm);
    esum += __shfl_xor(esum, 32);
    rsum = rsum * __expf(rmax - nm) + esum;
    rmax = nm;
  }
  if (hi == 0) { smax[w][l31] = rmax; ssum[w][l31] = rsum; }
  __syncthreads();
  if ((w & 1) == 0 && hi == 0) {
    const float ma = smax[w][l31], sa = ssum[w][l31];
    const float mb = smax[w ^ 1][l31], sb = ssum[w ^ 1][l31];
    const float M = fmaxf(ma, mb);
    const float l = sa * __expf(ma - M) + sb * __expf(mb - M);
    const size_t idx = (size_t)b * NPIX + mblk + m0 + l31;
    mstat[idx] = M;
    linv[idx] = 1.0f / l;
  }
}

// ---------- pass 2: recompute P = exp(S - m), O = P*V, +residual, write pa [B][C][N] ----------
__global__ __launch_bounds__(256) void attn_pv_k(const bh16* __restrict__ Qt,
                                                 const bh16* __restrict__ Kt,
                                                 const bh16* __restrict__ Vc,
                                                 const float* __restrict__ x,
                                                 const float* __restrict__ mstat,
                                                 const float* __restrict__ linv,
                                                 float* __restrict__ pa) {
  const int mblk = blockIdx.x * 64;
  const int cblk = blockIdx.y * 256;
  const int b = blockIdx.z;
  const int t = threadIdx.x;
  const int w = t >> 6, lane = t & 63, l31 = lane & 31, hi = lane >> 5;
  const int w64 = w << 6;
  __shared__ __align__(16) bh16 Qs[8 * 64 * 8];
  __shared__ __align__(16) bh16 Ks[8 * 64 * 8];
  __shared__ __align__(16) bh16 Ps[8 * 64 * 8];
  __shared__ __align__(16) bh16 Vs[8 * 256 * 8];
  __shared__ float linvL[64];

#pragma unroll
  for (int i = 0; i < 2; i++) {
    const int s = i * 256 + t;
    const int d8 = s >> 6, m = s & 63;
    glds16(Qt + ((size_t)(b * NPIX + mblk + m)) * CQK + d8 * 8, &Qs[(size_t)(i * 256 + w64) * 8]);
  }
  if (t < 64) linvL[t] = linv[(size_t)b * NPIX + mblk + t];

  const int j0 = (w & 1) * 32;    // GEMM1 subtile keys
  const int m0q = (w >> 1) * 32;  // GEMM1 subtile queries
  const int c0w = w * 64;         // GEMM2 channel strip (block-local)
  const float mst = mstat[(size_t)b * NPIX + mblk + m0q + l31];

  f32x16 o[2][2];
#pragma unroll
  for (int mt = 0; mt < 2; mt++)
#pragma unroll
    for (int ct = 0; ct < 2; ct++)
#pragma unroll
      for (int r = 0; r < 16; r++) o[mt][ct][r] = 0.0f;

  for (int n0 = 0; n0 < NPIX; n0 += 64) {
    __syncthreads();  // A: previous GEMM2 reads done
#pragma unroll
    for (int i = 0; i < 2; i++) {
      const int s = i * 256 + t;
      const int d8 = s >> 6, j = s & 63;
      glds16(Kt + ((size_t)(b * NPIX + n0 + j)) * CQK + d8 * 8, &Ks[(size_t)(i * 256 + w64) * 8]);
    }
#pragma unroll
    for (int i = 0; i < 8; i++) {
      const int s = i * 256 + t;
      const int j8 = s >> 8, c = s & 255;
      glds16(Vc + ((size_t)(b * CIN + cblk + c)) * NPIX + n0 + j8 * 8, &Vs[(size_t)(i * 256 + w64) * 8]);
    }
    __syncthreads();  // B: staging visible
    // GEMM1: S^T subtile
    f32x16 s1;
#pragma unroll
    for (int r = 0; r < 16; r++) s1[r] = 0.0f;
#pragma unroll
    for (int ks = 0; ks < 4; ks++) {
      bf16x8 a = *(const bf16x8*)&Ks[(size_t)((ks * 2 + hi) * 64 + j0 + l31) * 8];
      bf16x8 bq = *(const bf16x8*)&Qs[(size_t)((ks * 2 + hi) * 64 + m0q + l31) * 8];
      s1 = __builtin_amdgcn_mfma_f32_32x32x16_bf16(a, bq, s1, 0, 0, 0);
    }
    // P^T = exp(S^T - m), pack to LDS [j8][m][8]
#pragma unroll
    for (int g = 0; g < 4; g++) {
      union { bh16 h[4]; uint2 u2; } pk;
#pragma unroll
      for (int q = 0; q < 4; q++) pk.h[q] = (bh16)__expf(s1[g * 4 + q] - mst);
      *(uint2*)(void*)&Ps[(size_t)(((j0 >> 3) + g) * 64 + m0q + l31) * 8 + hi * 4] = pk.u2;
    }
    __syncthreads();  // C: P visible to all waves
    // GEMM2: O[m][c] += P[m][j] * V[j][c]
#pragma unroll
    for (int ks = 0; ks < 4; ks++) {
      bf16x8 pf0 = *(const bf16x8*)&Ps[(size_t)((ks * 2 + hi) * 64 + l31) * 8];
      bf16x8 pf1 = *(const bf16x8*)&Ps[(size_t)((ks * 2 + hi) * 64 + 32 + l31) * 8];
      bf16x8 vf0 = *(const bf16x8*)&Vs[(size_t)((ks * 2 + hi) * 256 + c0w + l31) * 8];
      bf16x8 vf1 = *(const bf16x8*)&Vs[(size_t)((ks * 2 + hi) * 256 + c0w + 32 + l31) * 8];
      o[0][0] = __builtin_amdgcn_mfma_f32_32x32x16_bf16(pf0, vf0, o[0][0], 0, 0, 0);
      o[0][1] = __builtin_amdgcn_mfma_f32_32x32x16_bf16(pf0, vf1, o[0][1], 0, 0, 0);
      o[1][0] = __builtin_amdgcn_mfma_f32_32x32x16_bf16(pf1, vf0, o[1][0], 0, 0, 0);
      o[1][1] = __builtin_amdgcn_mfma_f32_32x32x16_bf16(pf1, vf1, o[1][1], 0, 0, 0);
    }
  }
  // epilogue: *1/l + residual, write pa[B][C][N]
#pragma unroll
  for (int mt = 0; mt < 2; mt++) {
#pragma unroll
    for (int g = 0; g < 4; g++) {
      const int mloc = mt * 32 + g * 8 + hi * 4;
      const float4 lv = *(const float4*)&linvL[mloc];
#pragma unroll
      for (int ct = 0; ct < 2; ct++) {
        const size_t base = ((size_t)(b * CIN + cblk + c0w + ct * 32 + l31)) * NPIX + mblk + mloc;
        const float4 xv = *(const float4*)&x[base];
        float4 r;
        r.x = o[mt][ct][g * 4 + 0] * lv.x + xv.x;
        r.y = o[mt][ct][g * 4 + 1] * lv.y + xv.y;
        r.z = o[mt][ct][g * 4 + 2] * lv.z + xv.z;
        r.w = o[mt][ct][g * 4 + 3] * lv.w + xv.w;
        *(float4*)&pa[base] = r;
      }
    }
  }
}

// ---------- pooling: avg+max per (b,c) row of pa [B][C][N] ----------
__global__ __launch_bounds__(256) void pool2_k(const float* __restrict__ pa,
                                               float* __restrict__ avgv,
                                               float* __restrict__ maxv) {
  const int t = threadIdx.x;
  const int row = blockIdx.x * 4 + (t >> 6);
  const int lane = t & 63;
  const float* base = pa + (size_t)row * NPIX;
  float s = 0.0f, mx = -1e30f;
#pragma unroll
  for (int i = 0; i < 16; i++) {
    const float4 v = *(const float4*)(base + i * 256 + lane * 4);
    s += v.x + v.y + v.z + v.w;
    mx = fmaxf(mx, fmaxf(fmaxf(v.x, v.y), fmaxf(v.z, v.w)));
  }
#pragma unroll
  for (int d = 1; d < 64; d <<= 1) {
    s += __shfl_xor(s, d);
    mx = fmaxf(mx, __shfl_xor(mx, d));
  }
  if (lane == 0) {
    avgv[row] = s * (1.0f / 4096.0f);
    maxv[row] = mx;
  }
}

// ---------- channel-attention MLP -> sigmoid scale ----------
__global__ __launch_bounds__(256) void mlp2_k(const float* __restrict__ avgv,
                                              const float* __restrict__ maxv,
                                              const float* __restrict__ w1,
                                              const float* __restrict__ w2,
                                              float* __restrict__ scale) {
  const int b = blockIdx.x;
  const int t = threadIdx.x;
  __shared__ float avg_l[CIN], max_l[CIN], hbuf[128];
#pragma unroll
  for (int h = 0; h < 2; h++) {
    const int c = t + h * 256;
    avg_l[c] = avgv[b * CIN + c];
    max_l[c] = maxv[b * CIN + c];
  }
  __syncthreads();
  if (t < 128) {
    const float* src = (t < 64) ? avg_l : max_l;
    const int o = t & 63;
    float sacc = 0.0f;
    for (int c = 0; c < CIN; c++) sacc += w1[o * CIN + c] * src[c];
    hbuf[t] = fmaxf(sacc, 0.0f);
  }
  __syncthreads();
#pragma unroll
  for (int h = 0; h < 2; h++) {
    const int c = t + h * 256;
    float sacc = 0.0f;
#pragma unroll
    for (int k = 0; k < 64; k++) sacc += w2[c * 64 + k] * (hbuf[k] + hbuf[64 + k]);
    scale[b * CIN + c] = 1.0f / (1.0f + __expf(-sacc));
  }
}

// ---------- 3x3 conv + BN(eval) + ReLU, CA scale fused at input staging ----------
__global__ __launch_bounds__(256) void conv_k(const float* __restrict__ pa,
                                              const float* __restrict__ scale,
                                              const float* __restrict__ cw,
                                              const float* __restrict__ gamma,
                                              const float* __restrict__ beta,
                                              const float* __restrict__ mean,
                                              const float* __restrict__ var,
                                              float* __restrict__ out) {
  const int b = blockIdx.z;
  const int o0 = blockIdx.y * 16;
  const int bx = blockIdx.x;
  const int ty0 = (bx >> 2) * 32;
  const int tx0 = (bx & 3) * 16;
  const int t = threadIdx.x;
  __shared__ float in_s[8][612];
  __shared__ float w_s[1152];
  __shared__ float sb[16], bb[16];
  if (t < 16) {
    const int o = o0 + t;
    const float inv = rsqrtf(var[o] + 1e-5f);
    const float sc = inv * gamma[o];
    sb[t] = sc;
    bb[t] = beta[o] - mean[o] * sc;
  }
  float acc[2][16] = {};
  const int lx = t & 15;
  const int ly = t >> 4;
  for (int cc = 0; cc < CIN; cc += 8) {
    __syncthreads();
#pragma unroll
    for (int c = 0; c < 8; c++) {
      const float sc = scale[b * CIN + cc + c];
      const float* src = pa + ((size_t)(b * CIN + cc + c)) * NPIX;
      for (int pix = t; pix < 612; pix += 256) {
        const int py = pix / 18;
        const int px = pix - py * 18;
        const int gy = ty0 - 1 + py;
        const int gx = tx0 - 1 + px;
        float v = 0.0f;
        if (gy >= 0 && gy < 64 && gx >= 0 && gx < 64) v = src[gy * 64 + gx] * sc;
        in_s[c][pix] = v;
      }
    }
    for (int idx = t; idx < 1152; idx += 256) {
      const int o = idx / 72;
      const int r = idx - o * 72;
      w_s[r * 16 + o] = cw[(size_t)(o0 + o) * 4608 + cc * 9 + r];
    }
    __syncthreads();
#pragma unroll
    for (int c = 0; c < 8; c++) {
#pragma unroll
      for (int tap = 0; tap < 9; tap++) {
        const int ky = tap / 3, kx = tap - ky * 3;
        const float xv0 = in_s[c][(ly * 2 + ky) * 18 + lx + kx];
        const float xv1 = in_s[c][(ly * 2 + 1 + ky) * 18 + lx + kx];
        const float4* wp = (const float4*)&w_s[(c * 9 + tap) * 16];
        const float4 w0 = wp[0], w1 = wp[1], w2 = wp[2], w3 = wp[3];
        const float wv[16] = {w0.x, w0.y, w0.z, w0.w, w1.x, w1.y, w1.z, w1.w,
                              w2.x, w2.y, w2.z, w2.w, w3.x, w3.y, w3.z, w3.w};
#pragma unroll
        for (int o = 0; o < 16; o++) {
          acc[0][o] += xv0 * wv[o];
          acc[1][o] += xv1 * wv[o];
        }
      }
    }
  }
#pragma unroll
  for (int o = 0; o < 16; o++) {
    const float s = sb[o], bi = bb[o];
#pragma unroll
    for (int p = 0; p < 2; p++) {
      const int gy = ty0 + ly * 2 + p;
      const int gx = tx0 + lx;
      const float y = acc[p][o] * s + bi;
      out[((size_t)(b * COUT + o0 + o)) * NPIX + gy * 64 + gx] = fmaxf(y, 0.0f);
    }
  }
}

extern "C" void kernel_launch(void* const* d_in, const int* in_sizes, int n_in,
                              void* d_out, int out_size, void* d_ws, size_t ws_size,
                              hipStream_t stream) {
  (void)in_sizes; (void)n_in; (void)out_size; (void)ws_size;
  const float* x        = (const float*)d_in[0];
  const float* wq       = (const float*)d_in[1];
  const float* bq       = (const float*)d_in[2];
  const float* wk       = (const float*)d_in[3];
  const float* bk       = (const float*)d_in[4];
  const float* wv       = (const float*)d_in[5];
  const float* bv       = (const float*)d_in[6];
  const float* ca_w1    = (const float*)d_in[7];
  const float* ca_w2    = (const float*)d_in[8];
  const float* conv_w   = (const float*)d_in[9];
  const float* bn_gamma = (const float*)d_in[10];
  const float* bn_beta  = (const float*)d_in[11];
  const float* bn_mean  = (const float*)d_in[12];
  const float* bn_var   = (const float*)d_in[13];
  float* out = (float*)d_out;

  float* ws = (float*)d_ws;
  float* xT   = ws;                       // [B][N][C] fp32, 8388608 floats; aliased by pa
  float* pa   = xT;                       // [B][C][N] fp32 (xT dead after Q/K gemms)
  bh16* Qt    = (bh16*)(ws + 8388608);    // [B][N][64] bf16
  bh16* Kt    = (bh16*)(ws + 8912896);    // [B][N][64] bf16
  bh16* Vc    = (bh16*)(ws + 9437184);    // [B][C][N] bf16
  float* mst  = ws + 13631488;            // [B][N]
  float* linv = ws + 13647872;            // [B][N]
  float* avgv = ws + 13664256;            // [B][C]
  float* maxv = ws + 13666304;            // [B][C]
  float* scl  = ws + 13668352;            // [B][C]

  const dim3 tb(32, 8, 1);
  transpose_k<<<dim3(NPIX / 32, CIN / 32, NB), tb, 0, stream>>>(x, xT, CIN, NPIX);
  gemm_qkv_k<<<dim3(256, 1, 1), 256, 0, stream>>>(xT, wq, bq, Qt, 64);
  gemm_qkv_k<<<dim3(256, 1, 1), 256, 0, stream>>>(xT, wk, bk, Kt, 64);
  gemm_v_k<<<dim3(64, 8, NB), 256, 0, stream>>>(x, wv, bv, Vc);
  attn_stats_k<<<dim3(64, NB, 1), 256, 0, stream>>>(Qt, Kt, mst, linv);
  attn_pv_k<<<dim3(64, 2, NB), 256, 0, stream>>>(Qt, Kt, Vc, x, mst, linv, pa);
  pool2_k<<<dim3(512, 1, 1), 256, 0, stream>>>(pa, avgv, maxv);
  mlp2_k<<<dim3(NB, 1, 1), 256, 0, stream>>>(avgv, maxv, ca_w1, ca_w2, scl);
  conv_k<<<dim3(8, 16, NB), 256, 0, stream>>>(pa, scl, conv_w, bn_gamma, bn_beta,
                                              bn_mean, bn_var, out);
}

// Round 3
// 617.790 us; speedup vs baseline: 3.9377x; 2.5130x over previous
//
#include <hip/hip_runtime.h>

#define NB 4
#define CIN 512
#define NPIX 4096
#define CQK 64
#define COUT 256
#define PPIX 4356   // 66*66 padded pixels

typedef __bf16 bh16;
typedef _Float16 fh16;
typedef __attribute__((ext_vector_type(8))) __bf16 bf16x8;
typedef __attribute__((ext_vector_type(8))) _Float16 f16x8;
typedef __attribute__((ext_vector_type(16))) float f32x16;

#define AS1 __attribute__((address_space(1)))
#define AS3 __attribute__((address_space(3)))

__device__ __forceinline__ void glds16(const void* g, void* l) {
  __builtin_amdgcn_global_load_lds((const AS1 unsigned int*)g, (AS3 unsigned int*)l, 16, 0, 0);
}

// ---------- transpose per batch: src [rows][cols] -> dst [cols][rows] ----------
__global__ __launch_bounds__(256) void transpose_k(const float* __restrict__ src,
                                                   float* __restrict__ dst,
                                                   int rows, int cols) {
  __shared__ float tile[32][33];
  const int b = blockIdx.z;
  const int c0 = blockIdx.x * 32;
  const int r0 = blockIdx.y * 32;
  const float* s = src + (size_t)b * rows * cols;
  float* d = dst + (size_t)b * rows * cols;
  const int tx = threadIdx.x, ty = threadIdx.y;  // 32 x 8
#pragma unroll
  for (int i = 0; i < 32; i += 8)
    tile[ty + i][tx] = s[(size_t)(r0 + ty + i) * cols + (c0 + tx)];
  __syncthreads();
#pragma unroll
  for (int i = 0; i < 32; i += 8)
    d[(size_t)(c0 + ty + i) * rows + (r0 + tx)] = tile[tx][ty + i];
}

// ---------- Q/K projection: out[r][o] = sum_c A[r][c]*W[o][c] + bias[o], bf16 out ----------
__global__ __launch_bounds__(256) void gemm_qkv_k(const float* __restrict__ A,
                                                  const float* __restrict__ W,
                                                  const float* __restrict__ bias,
                                                  bh16* __restrict__ out, int O) {
  __shared__ float As[16][68];
  __shared__ float Bs[16][68];
  const int r0 = blockIdx.x * 64;
  const int o0 = blockIdx.y * 64;
  const int t = threadIdx.x;
  const int tx = t & 15, ty = t >> 4;
  const int li = t >> 2;
  const int lu = (t & 3) * 4;
  float acc[4][4] = {};
  for (int kc = 0; kc < CIN; kc += 16) {
    float4 av = *(const float4*)(A + (size_t)(r0 + li) * CIN + kc + lu);
    float4 bv = *(const float4*)(W + (size_t)(o0 + li) * CIN + kc + lu);
    __syncthreads();
    As[lu + 0][li] = av.x; As[lu + 1][li] = av.y; As[lu + 2][li] = av.z; As[lu + 3][li] = av.w;
    Bs[lu + 0][li] = bv.x; Bs[lu + 1][li] = bv.y; Bs[lu + 2][li] = bv.z; Bs[lu + 3][li] = bv.w;
    __syncthreads();
#pragma unroll
    for (int k = 0; k < 16; k++) {
      const float4 a4 = *(const float4*)&As[k][ty * 4];
      const float4 b4 = *(const float4*)&Bs[k][tx * 4];
      const float aa[4] = {a4.x, a4.y, a4.z, a4.w};
      const float bb[4] = {b4.x, b4.y, b4.z, b4.w};
#pragma unroll
      for (int u = 0; u < 4; u++)
#pragma unroll
        for (int v = 0; v < 4; v++) acc[u][v] += aa[u] * bb[v];
    }
  }
#pragma unroll
  for (int u = 0; u < 4; u++) {
    union { bh16 h[4]; uint2 u2; } pk;
#pragma unroll
    for (int v = 0; v < 4; v++) pk.h[v] = (bh16)(acc[u][v] + bias[o0 + tx * 4 + v]);
    *(uint2*)(void*)(out + (size_t)(r0 + ty * 4 + u) * O + o0 + tx * 4) = pk.u2;
  }
}

// ---------- V projection: Vc[o][n] = sum_c wv[o][c]*x[c][n] + bv[o], bf16 [B][C][N] ----------
__global__ __launch_bounds__(256) void gemm_v_k(const float* __restrict__ x,
                                                const float* __restrict__ wv,
                                                const float* __restrict__ bv,
                                                bh16* __restrict__ Vc) {
  __shared__ float As[16][68];
  __shared__ float Bs[16][68];
  const int n0 = blockIdx.x * 64;
  const int o0 = blockIdx.y * 64;
  const int b = blockIdx.z;
  const int t = threadIdx.x;
  const int tx = t & 15, ty = t >> 4;
  const int li = t >> 2;
  const int lu = (t & 3) * 4;
  float acc[4][4] = {};
  for (int kc = 0; kc < CIN; kc += 16) {
    float4 av = *(const float4*)(wv + (size_t)(o0 + li) * CIN + kc + lu);
    float4 bx = *(const float4*)(x + ((size_t)b * CIN + kc + ty) * NPIX + n0 + tx * 4);
    __syncthreads();
    As[lu + 0][li] = av.x; As[lu + 1][li] = av.y; As[lu + 2][li] = av.z; As[lu + 3][li] = av.w;
    *(float4*)&Bs[ty][tx * 4] = bx;
    __syncthreads();
#pragma unroll
    for (int k = 0; k < 16; k++) {
      const float4 a4 = *(const float4*)&As[k][ty * 4];
      const float4 b4 = *(const float4*)&Bs[k][tx * 4];
      const float aa[4] = {a4.x, a4.y, a4.z, a4.w};
      const float bb[4] = {b4.x, b4.y, b4.z, b4.w};
#pragma unroll
      for (int u = 0; u < 4; u++)
#pragma unroll
        for (int v = 0; v < 4; v++) acc[u][v] += aa[u] * bb[v];
    }
  }
#pragma unroll
  for (int u = 0; u < 4; u++) {
    const int o = o0 + ty * 4 + u;
    union { bh16 h[4]; uint2 u2; } pk;
#pragma unroll
    for (int v = 0; v < 4; v++) pk.h[v] = (bh16)(acc[u][v] + bv[o]);
    *(uint2*)(void*)(Vc + ((size_t)(b * CIN + o)) * NPIX + n0 + tx * 4) = pk.u2;
  }
}

// ---------- pass 1: softmax stats via MFMA QK^T ----------
__global__ __launch_bounds__(256) void attn_stats_k(const bh16* __restrict__ Qt,
                                                    const bh16* __restrict__ Kt,
                                                    float* __restrict__ mstat,
                                                    float* __restrict__ linv) {
  const int mblk = blockIdx.x * 64;
  const int b = blockIdx.y;
  const int t = threadIdx.x;
  const int w = t >> 6, lane = t & 63, l31 = lane & 31, hi = lane >> 5;
  const int w64 = w << 6;
  __shared__ __align__(16) bh16 Qs[8 * 64 * 8];
  __shared__ __align__(16) bh16 Ks[8 * 64 * 8];
  __shared__ float smax[4][32], ssum[4][32];

#pragma unroll
  for (int i = 0; i < 2; i++) {
    const int s = i * 256 + t;
    const int d8 = s >> 6, m = s & 63;
    glds16(Qt + ((size_t)(b * NPIX + mblk + m)) * CQK + d8 * 8, &Qs[(size_t)(i * 256 + w64) * 8]);
  }
  const int j0 = (w & 1) * 32;
  const int m0 = (w >> 1) * 32;
  float rmax = -1e30f, rsum = 0.0f;

  for (int n0 = 0; n0 < NPIX; n0 += 64) {
    __syncthreads();
#pragma unroll
    for (int i = 0; i < 2; i++) {
      const int s = i * 256 + t;
      const int d8 = s >> 6, j = s & 63;
      glds16(Kt + ((size_t)(b * NPIX + n0 + j)) * CQK + d8 * 8, &Ks[(size_t)(i * 256 + w64) * 8]);
    }
    __syncthreads();
    f32x16 s1;
#pragma unroll
    for (int r = 0; r < 16; r++) s1[r] = 0.0f;
#pragma unroll
    for (int ks = 0; ks < 4; ks++) {
      bf16x8 a = *(const bf16x8*)&Ks[(size_t)((ks * 2 + hi) * 64 + j0 + l31) * 8];
      bf16x8 bq = *(const bf16x8*)&Qs[(size_t)((ks * 2 + hi) * 64 + m0 + l31) * 8];
      s1 = __builtin_amdgcn_mfma_f32_32x32x16_bf16(a, bq, s1, 0, 0, 0);
    }
    float tmax = s1[0];
#pragma unroll
    for (int r = 1; r < 16; r++) tmax = fmaxf(tmax, s1[r]);
    tmax = fmaxf(tmax, __shfl_xor(tmax, 32));
    const float nm = fmaxf(rmax, tmax);
    float esum = 0.0f;
#pragma unroll
    for (int r = 0; r < 16; r++) esum += __expf(s1[r] - nm);
    esum += __shfl_xor(esum, 32);
    rsum = rsum * __expf(rmax - nm) + esum;
    rmax = nm;
  }
  if (hi == 0) { smax[w][l31] = rmax; ssum[w][l31] = rsum; }
  __syncthreads();
  if ((w & 1) == 0 && hi == 0) {
    const float ma = smax[w][l31], sa = ssum[w][l31];
    const float mb = smax[w ^ 1][l31], sb = ssum[w ^ 1][l31];
    const float M = fmaxf(ma, mb);
    const float l = sa * __expf(ma - M) + sb * __expf(mb - M);
    const size_t idx = (size_t)b * NPIX + mblk + m0 + l31;
    mstat[idx] = M;
    linv[idx] = 1.0f / l;
  }
}

// ---------- pass 2: P = exp(S - m), O = P*V, +residual, write pa [B][C][N] ----------
__global__ __launch_bounds__(256) void attn_pv_k(const bh16* __restrict__ Qt,
                                                 const bh16* __restrict__ Kt,
                                                 const bh16* __restrict__ Vc,
                                                 const float* __restrict__ x,
                                                 const float* __restrict__ mstat,
                                                 const float* __restrict__ linv,
                                                 float* __restrict__ pa) {
  const int mblk = blockIdx.x * 64;
  const int cblk = blockIdx.y * 256;
  const int b = blockIdx.z;
  const int t = threadIdx.x;
  const int w = t >> 6, lane = t & 63, l31 = lane & 31, hi = lane >> 5;
  const int w64 = w << 6;
  __shared__ __align__(16) bh16 Qs[8 * 64 * 8];
  __shared__ __align__(16) bh16 Ks[8 * 64 * 8];
  __shared__ __align__(16) bh16 Ps[8 * 64 * 8];
  __shared__ __align__(16) bh16 Vs[8 * 256 * 8];
  __shared__ float linvL[64];

#pragma unroll
  for (int i = 0; i < 2; i++) {
    const int s = i * 256 + t;
    const int d8 = s >> 6, m = s & 63;
    glds16(Qt + ((size_t)(b * NPIX + mblk + m)) * CQK + d8 * 8, &Qs[(size_t)(i * 256 + w64) * 8]);
  }
  if (t < 64) linvL[t] = linv[(size_t)b * NPIX + mblk + t];

  const int j0 = (w & 1) * 32;
  const int m0q = (w >> 1) * 32;
  const int c0w = w * 64;
  const float mst = mstat[(size_t)b * NPIX + mblk + m0q + l31];

  f32x16 o[2][2];
#pragma unroll
  for (int mt = 0; mt < 2; mt++)
#pragma unroll
    for (int ct = 0; ct < 2; ct++)
#pragma unroll
      for (int r = 0; r < 16; r++) o[mt][ct][r] = 0.0f;

  for (int n0 = 0; n0 < NPIX; n0 += 64) {
    __syncthreads();
#pragma unroll
    for (int i = 0; i < 2; i++) {
      const int s = i * 256 + t;
      const int d8 = s >> 6, j = s & 63;
      glds16(Kt + ((size_t)(b * NPIX + n0 + j)) * CQK + d8 * 8, &Ks[(size_t)(i * 256 + w64) * 8]);
    }
#pragma unroll
    for (int i = 0; i < 8; i++) {
      const int s = i * 256 + t;
      const int j8 = s >> 8, c = s & 255;
      glds16(Vc + ((size_t)(b * CIN + cblk + c)) * NPIX + n0 + j8 * 8, &Vs[(size_t)(i * 256 + w64) * 8]);
    }
    __syncthreads();
    f32x16 s1;
#pragma unroll
    for (int r = 0; r < 16; r++) s1[r] = 0.0f;
#pragma unroll
    for (int ks = 0; ks < 4; ks++) {
      bf16x8 a = *(const bf16x8*)&Ks[(size_t)((ks * 2 + hi) * 64 + j0 + l31) * 8];
      bf16x8 bq = *(const bf16x8*)&Qs[(size_t)((ks * 2 + hi) * 64 + m0q + l31) * 8];
      s1 = __builtin_amdgcn_mfma_f32_32x32x16_bf16(a, bq, s1, 0, 0, 0);
    }
#pragma unroll
    for (int g = 0; g < 4; g++) {
      union { bh16 h[4]; uint2 u2; } pk;
#pragma unroll
      for (int q = 0; q < 4; q++) pk.h[q] = (bh16)__expf(s1[g * 4 + q] - mst);
      *(uint2*)(void*)&Ps[(size_t)(((j0 >> 3) + g) * 64 + m0q + l31) * 8 + hi * 4] = pk.u2;
    }
    __syncthreads();
#pragma unroll
    for (int ks = 0; ks < 4; ks++) {
      bf16x8 pf0 = *(const bf16x8*)&Ps[(size_t)((ks * 2 + hi) * 64 + l31) * 8];
      bf16x8 pf1 = *(const bf16x8*)&Ps[(size_t)((ks * 2 + hi) * 64 + 32 + l31) * 8];
      bf16x8 vf0 = *(const bf16x8*)&Vs[(size_t)((ks * 2 + hi) * 256 + c0w + l31) * 8];
      bf16x8 vf1 = *(const bf16x8*)&Vs[(size_t)((ks * 2 + hi) * 256 + c0w + 32 + l31) * 8];
      o[0][0] = __builtin_amdgcn_mfma_f32_32x32x16_bf16(pf0, vf0, o[0][0], 0, 0, 0);
      o[0][1] = __builtin_amdgcn_mfma_f32_32x32x16_bf16(pf0, vf1, o[0][1], 0, 0, 0);
      o[1][0] = __builtin_amdgcn_mfma_f32_32x32x16_bf16(pf1, vf0, o[1][0], 0, 0, 0);
      o[1][1] = __builtin_amdgcn_mfma_f32_32x32x16_bf16(pf1, vf1, o[1][1], 0, 0, 0);
    }
  }
#pragma unroll
  for (int mt = 0; mt < 2; mt++) {
#pragma unroll
    for (int g = 0; g < 4; g++) {
      const int mloc = mt * 32 + g * 8 + hi * 4;
      const float4 lv = *(const float4*)&linvL[mloc];
#pragma unroll
      for (int ct = 0; ct < 2; ct++) {
        const size_t base = ((size_t)(b * CIN + cblk + c0w + ct * 32 + l31)) * NPIX + mblk + mloc;
        const float4 xv = *(const float4*)&x[base];
        float4 r;
        r.x = o[mt][ct][g * 4 + 0] * lv.x + xv.x;
        r.y = o[mt][ct][g * 4 + 1] * lv.y + xv.y;
        r.z = o[mt][ct][g * 4 + 2] * lv.z + xv.z;
        r.w = o[mt][ct][g * 4 + 3] * lv.w + xv.w;
        *(float4*)&pa[base] = r;
      }
    }
  }
}

// ---------- pooling: avg+max per (b,c) row of pa [B][C][N] ----------
__global__ __launch_bounds__(256) void pool2_k(const float* __restrict__ pa,
                                               float* __restrict__ avgv,
                                               float* __restrict__ maxv) {
  const int t = threadIdx.x;
  const int row = blockIdx.x * 4 + (t >> 6);
  const int lane = t & 63;
  const float* base = pa + (size_t)row * NPIX;
  float s = 0.0f, mx = -1e30f;
#pragma unroll
  for (int i = 0; i < 16; i++) {
    const float4 v = *(const float4*)(base + i * 256 + lane * 4);
    s += v.x + v.y + v.z + v.w;
    mx = fmaxf(mx, fmaxf(fmaxf(v.x, v.y), fmaxf(v.z, v.w)));
  }
#pragma unroll
  for (int d = 1; d < 64; d <<= 1) {
    s += __shfl_xor(s, d);
    mx = fmaxf(mx, __shfl_xor(mx, d));
  }
  if (lane == 0) {
    avgv[row] = s * (1.0f / 4096.0f);
    maxv[row] = mx;
  }
}

// ---------- channel-attention MLP -> sigmoid scale ----------
__global__ __launch_bounds__(256) void mlp2_k(const float* __restrict__ avgv,
                                              const float* __restrict__ maxv,
                                              const float* __restrict__ w1,
                                              const float* __restrict__ w2,
                                              float* __restrict__ scale) {
  const int b = blockIdx.x;
  const int t = threadIdx.x;
  __shared__ float avg_l[CIN], max_l[CIN], hbuf[128];
#pragma unroll
  for (int h = 0; h < 2; h++) {
    const int c = t + h * 256;
    avg_l[c] = avgv[b * CIN + c];
    max_l[c] = maxv[b * CIN + c];
  }
  __syncthreads();
  if (t < 128) {
    const float* src = (t < 64) ? avg_l : max_l;
    const int o = t & 63;
    float sacc = 0.0f;
    for (int c = 0; c < CIN; c++) sacc += w1[o * CIN + c] * src[c];
    hbuf[t] = fmaxf(sacc, 0.0f);
  }
  __syncthreads();
#pragma unroll
  for (int h = 0; h < 2; h++) {
    const int c = t + h * 256;
    float sacc = 0.0f;
#pragma unroll
    for (int k = 0; k < 64; k++) sacc += w2[c * 64 + k] * (hbuf[k] + hbuf[64 + k]);
    scale[b * CIN + c] = 1.0f / (1.0f + __expf(-sacc));
  }
}

// ---------- pack pa*scale -> f16 padded pixel-major [B][66*66][512] ----------
__global__ __launch_bounds__(256) void pack_k(const float* __restrict__ pa,
                                              const float* __restrict__ scl,
                                              fh16* __restrict__ pab) {
  __shared__ float tile[32][65];
  const int n0 = blockIdx.x * 32;
  const int c0 = blockIdx.y * 64;
  const int b = blockIdx.z;
  const int t = threadIdx.x;
  {
    const int px = t & 31, cc = t >> 5;
#pragma unroll
    for (int i = 0; i < 8; i++) {
      const int c = cc * 8 + i;
      tile[px][c] = pa[((size_t)(b * CIN + c0 + c)) * NPIX + n0 + px] * scl[b * CIN + c0 + c];
    }
  }
  __syncthreads();
  {
    const int pixr = t >> 5, c2 = (t & 31) * 2;
#pragma unroll
    for (int j = 0; j < 4; j++) {
      const int pix = pixr + j * 8;
      const int n = n0 + pix;
      const int pp = ((n >> 6) + 1) * 66 + (n & 63) + 1;
      union { fh16 h[2]; unsigned int u; } pk;
      pk.h[0] = (fh16)tile[pix][c2];
      pk.h[1] = (fh16)tile[pix][c2 + 1];
      *(unsigned int*)(void*)(pab + ((size_t)b * PPIX + pp) * CIN + c0 + c2) = pk.u;
    }
  }
}

// ---------- repack conv weights -> f16 [oblk4][chunk32][tap9][o64][c16] ----------
__global__ __launch_bounds__(256) void wpack_k(const float* __restrict__ cw,
                                               fh16* __restrict__ wp) {
  const int d0 = (blockIdx.x * 256 + threadIdx.x) * 8;
  const int cc = d0 & 15;
  const int q = d0 >> 4;
  const int o = q & 63;
  const int q2 = q >> 6;
  const int tap = q2 % 9;
  const int q3 = q2 / 9;
  const int chunk = q3 & 31;
  const int oblk = q3 >> 5;
  const size_t sbase = (size_t)(oblk * 64 + o) * 4608 + (size_t)(chunk * 16 + cc) * 9 + tap;
  union { fh16 h[8]; uint4 u4; } pk;
#pragma unroll
  for (int i = 0; i < 8; i++) pk.h[i] = (fh16)cw[sbase + (size_t)i * 9];
  *(uint4*)(void*)(wp + d0) = pk.u4;
}

// ---------- implicit-GEMM 3x3 conv via f16 MFMA + BN + ReLU ----------
// block: 64 cout x 256 pix (4 image rows); wave w = image row y0+w.
__global__ __launch_bounds__(256) void conv_mfma_k(const fh16* __restrict__ pab,
                                                   const fh16* __restrict__ wp,
                                                   const float* __restrict__ gamma,
                                                   const float* __restrict__ beta,
                                                   const float* __restrict__ mean,
                                                   const float* __restrict__ var,
                                                   float* __restrict__ out) {
  const int y0 = blockIdx.x * 4;
  const int oblk = blockIdx.y;
  const int b = blockIdx.z;
  const int t = threadIdx.x;
  const int w = t >> 6, lane = t & 63, l31 = lane & 31, hi = lane >> 5;
  __shared__ __align__(16) fh16 Xs[2][416 * 16];   // [buf][lpix][16c]  13312 B each
  __shared__ __align__(16) fh16 Ws[2][9 * 64 * 16]; // [buf][tap][o][16c] 18432 B each
  __shared__ float sb[64], bb[64];
  if (t < 64) {
    const int o = oblk * 64 + t;
    const float inv = rsqrtf(var[o] + 1e-5f);
    const float sc = inv * gamma[o];
    sb[t] = sc;
    bb[t] = beta[o] - mean[o] * sc;
  }
  f32x16 o00, o01, o10, o11;
#pragma unroll
  for (int r = 0; r < 16; r++) { o00[r] = 0.0f; o01[r] = 0.0f; o10[r] = 0.0f; o11[r] = 0.0f; }

  const fh16* xbase = pab + ((size_t)b * PPIX + y0 * 66) * CIN + (lane >> 1) * CIN + (lane & 1) * 8;
  const fh16* wbase = wp + (size_t)oblk * 32 * 9216 + lane * 8;

#define STAGE(chunk, buf)                                                        \
  {                                                                              \
    const fh16* xs = xbase + (chunk) * 16;                                       \
    for (int i = w; i < 13; i += 4)                                              \
      glds16(xs + (size_t)i * 32 * CIN, &Xs[buf][i * 512]);                      \
    const fh16* wsrc = wbase + (size_t)(chunk) * 9216;                           \
    for (int i = w; i < 18; i += 4)                                              \
      glds16(wsrc + (size_t)i * 512, &Ws[buf][i * 512]);                         \
  }

  STAGE(0, 0);
  __syncthreads();
  for (int chunk = 0; chunk < 32; chunk++) {
    if (chunk < 31) STAGE(chunk + 1, (chunk + 1) & 1);
    const fh16* xs = Xs[chunk & 1];
    const fh16* ws = Ws[chunk & 1];
#pragma unroll
    for (int tap = 0; tap < 9; tap++) {
      const int ky = tap / 3, kx = tap - ky * 3;
      const f16x8 a0 = *(const f16x8*)&ws[tap * 1024 + l31 * 16 + hi * 8];
      const f16x8 a1 = *(const f16x8*)&ws[tap * 1024 + (32 + l31) * 16 + hi * 8];
      const int px = ((w + ky) * 66 + l31 + kx) * 16 + hi * 8;
      const f16x8 b0 = *(const f16x8*)&xs[px];
      const f16x8 b1 = *(const f16x8*)&xs[px + 32 * 16];
      o00 = __builtin_amdgcn_mfma_f32_32x32x16_f16(a0, b0, o00, 0, 0, 0);
      o01 = __builtin_amdgcn_mfma_f32_32x32x16_f16(a0, b1, o01, 0, 0, 0);
      o10 = __builtin_amdgcn_mfma_f32_32x32x16_f16(a1, b0, o10, 0, 0, 0);
      o11 = __builtin_amdgcn_mfma_f32_32x32x16_f16(a1, b1, o11, 0, 0, 0);
    }
    __syncthreads();
  }
#undef STAGE

  const f32x16* accs[2][2] = {{&o00, &o01}, {&o10, &o11}};
#pragma unroll
  for (int mt = 0; mt < 2; mt++) {
#pragma unroll
    for (int nt = 0; nt < 2; nt++) {
      const f32x16& A = *accs[mt][nt];
#pragma unroll
      for (int r = 0; r < 16; r++) {
        const int cl = mt * 32 + (r & 3) + 8 * (r >> 2) + 4 * hi;
        const int pix = nt * 32 + l31;
        const float y = A[r] * sb[cl] + bb[cl];
        out[((size_t)(b * COUT + oblk * 64 + cl)) * NPIX + (y0 + w) * 64 + pix] = fmaxf(y, 0.0f);
      }
    }
  }
}

extern "C" void kernel_launch(void* const* d_in, const int* in_sizes, int n_in,
                              void* d_out, int out_size, void* d_ws, size_t ws_size,
                              hipStream_t stream) {
  (void)in_sizes; (void)n_in; (void)out_size; (void)ws_size;
  const float* x        = (const float*)d_in[0];
  const float* wq       = (const float*)d_in[1];
  const float* bq       = (const float*)d_in[2];
  const float* wk       = (const float*)d_in[3];
  const float* bk       = (const float*)d_in[4];
  const float* wv       = (const float*)d_in[5];
  const float* bv       = (const float*)d_in[6];
  const float* ca_w1    = (const float*)d_in[7];
  const float* ca_w2    = (const float*)d_in[8];
  const float* conv_w   = (const float*)d_in[9];
  const float* bn_gamma = (const float*)d_in[10];
  const float* bn_beta  = (const float*)d_in[11];
  const float* bn_mean  = (const float*)d_in[12];
  const float* bn_var   = (const float*)d_in[13];
  float* out = (float*)d_out;

  float* ws = (float*)d_ws;
  float* xT   = ws;                       // [B][N][C] fp32; aliased by pa
  float* pa   = xT;                       // [B][C][N] fp32
  bh16* Qt    = (bh16*)(ws + 8388608);
  bh16* Kt    = (bh16*)(ws + 8912896);
  bh16* Vc    = (bh16*)(ws + 9437184);
  float* mst  = ws + 13631488;
  float* linv = ws + 13647872;
  float* avgv = ws + 13664256;
  float* maxv = ws + 13666304;
  float* scl  = ws + 13668352;
  fh16* pab   = (fh16*)(ws + 13670400);   // [B][4356][512] f16 + pad
  fh16* wpck  = (fh16*)(ws + 18139136);   // [4][32][9][64][16] f16

  // zero padded borders of pab (17.87 MB incl. tail pad)
  hipMemsetAsync(pab, 0, (size_t)(NB * PPIX * CIN + 16384) * sizeof(fh16), stream);
  wpack_k<<<dim3(576, 1, 1), 256, 0, stream>>>(conv_w, wpck);

  const dim3 tb(32, 8, 1);
  transpose_k<<<dim3(NPIX / 32, CIN / 32, NB), tb, 0, stream>>>(x, xT, CIN, NPIX);
  gemm_qkv_k<<<dim3(256, 1, 1), 256, 0, stream>>>(xT, wq, bq, Qt, 64);
  gemm_qkv_k<<<dim3(256, 1, 1), 256, 0, stream>>>(xT, wk, bk, Kt, 64);
  gemm_v_k<<<dim3(64, 8, NB), 256, 0, stream>>>(x, wv, bv, Vc);
  attn_stats_k<<<dim3(64, NB, 1), 256, 0, stream>>>(Qt, Kt, mst, linv);
  attn_pv_k<<<dim3(64, 2, NB), 256, 0, stream>>>(Qt, Kt, Vc, x, mst, linv, pa);
  pool2_k<<<dim3(512, 1, 1), 256, 0, stream>>>(pa, avgv, maxv);
  mlp2_k<<<dim3(NB, 1, 1), 256, 0, stream>>>(avgv, maxv, ca_w1, ca_w2, scl);
  pack_k<<<dim3(NPIX / 32, CIN / 64, NB), 256, 0, stream>>>(pa, scl, pab);
  conv_mfma_k<<<dim3(16, 4, NB), 256, 0, stream>>>(pab, wpck, bn_gamma, bn_beta,
                                                   bn_mean, bn_var, out);
}